// Round 8
// baseline (279.164 us; speedup 1.0000x reference)
//
#include <hip/hip_runtime.h>
#include <hip/hip_bf16.h>

typedef unsigned short u16;
typedef __attribute__((ext_vector_type(4))) float f32x4;
typedef __attribute__((ext_vector_type(8))) short bf16x8;

#define SEQ 2048
#define DM 1024
#define DKK 64
#define NH 16
#define DFF 2048
#define TOK 4096

#define AS1 __attribute__((address_space(1)))
#define AS3 __attribute__((address_space(3)))

#define MFMA16(a, b, c) __builtin_amdgcn_mfma_f32_16x16x32_bf16((a), (b), (c), 0, 0, 0)

__device__ __forceinline__ u16 f2b(float f) {
  unsigned u = __float_as_uint(f);
  u = u + 0x7fffu + ((u >> 16) & 1u);
  return (u16)(u >> 16);
}

__device__ __forceinline__ unsigned cvtpk(float lo, float hi) {
  unsigned r;
  asm("v_cvt_pk_bf16_f32 %0, %1, %2" : "=v"(r) : "v"(lo), "v"(hi));
  return r;
}

__device__ __forceinline__ void gload_lds16(const u16* g, u16* l) {
  __builtin_amdgcn_global_load_lds((AS1 unsigned*)(size_t)g, (AS3 unsigned*)l, 16, 0, 0);
}

// ---------------- batched weight transpose fp32 [K,N] -> bf16 [N,K] ----------------
__global__ __launch_bounds__(256)
void transpose_all(const float* __restrict__ Wq, const float* __restrict__ Wk,
                   const float* __restrict__ Wv, const float* __restrict__ Wo,
                   const float* __restrict__ W1, const float* __restrict__ W2,
                   u16* __restrict__ Wqkt, u16* __restrict__ Wvt, u16* __restrict__ Wot,
                   u16* __restrict__ W1t, u16* __restrict__ W2t) {
  const int bid = blockIdx.x;
  const float* src;
  u16* dst;
  int K, N, lb;
  if (bid < 1024)      { src = Wq; dst = Wqkt;                 K = 1024; N = 1024; lb = bid; }
  else if (bid < 2048) { src = Wk; dst = Wqkt + (1 << 20);     K = 1024; N = 1024; lb = bid - 1024; }
  else if (bid < 3072) { src = Wv; dst = Wvt;                  K = 1024; N = 1024; lb = bid - 2048; }
  else if (bid < 4096) { src = Wo; dst = Wot;                  K = 1024; N = 1024; lb = bid - 3072; }
  else if (bid < 6144) { src = W1; dst = W1t;                  K = 1024; N = 2048; lb = bid - 4096; }
  else                 { src = W2; dst = W2t;                  K = 2048; N = 1024; lb = bid - 6144; }
  const int nx = N / 32;
  const int n0 = (lb % nx) * 32, k0 = (lb / nx) * 32;
  __shared__ float t[32][33];
  const int tx = threadIdx.x, ty = threadIdx.y;
#pragma unroll
  for (int i = 0; i < 4; i++) {
    int k = ty + i * 8;
    t[k][tx] = src[(size_t)(k0 + k) * N + n0 + tx];
  }
  __syncthreads();
#pragma unroll
  for (int i = 0; i < 4; i++) {
    int n = ty + i * 8;
    dst[(size_t)(n0 + n) * K + k0 + tx] = f2b(t[tx][n]);
  }
}

// ---------------- LayerNorm ----------------
__global__ __launch_bounds__(256)
void ln_kernel(const float* __restrict__ x, const float* __restrict__ alpha,
               const float* __restrict__ beta, u16* __restrict__ out) {
  const int row = blockIdx.x;
  const float4 v = ((const float4*)(x + (size_t)row * DM))[threadIdx.x];
  float s = v.x + v.y + v.z + v.w;
  float q = v.x * v.x + v.y * v.y + v.z * v.z + v.w * v.w;
#pragma unroll
  for (int off = 1; off < 64; off <<= 1) {
    s += __shfl_xor(s, off);
    q += __shfl_xor(q, off);
  }
  __shared__ float ss[4], qq[4];
  const int wid = threadIdx.x >> 6;
  if ((threadIdx.x & 63) == 0) { ss[wid] = s; qq[wid] = q; }
  __syncthreads();
  s = ss[0] + ss[1] + ss[2] + ss[3];
  q = qq[0] + qq[1] + qq[2] + qq[3];
  const float mean = s * (1.f / DM);
  float var = (q - (float)DM * mean * mean) * (1.f / (DM - 1));
  var = fmaxf(var, 0.f);
  const float inv = 1.f / (sqrtf(var) + 1e-6f);
  const float4 a4 = ((const float4*)alpha)[threadIdx.x];
  const float4 b4 = ((const float4*)beta)[threadIdx.x];
  ushort4 o;
  o.x = f2b((v.x - mean) * inv * a4.x + b4.x);
  o.y = f2b((v.y - mean) * inv * a4.y + b4.y);
  o.z = f2b((v.z - mean) * inv * a4.z + b4.z);
  o.w = f2b((v.w - mean) * inv * a4.w + b4.w);
  ((ushort4*)(out + (size_t)row * DM))[threadIdx.x] = o;
}

// ---------------- GEMM: C[M,N] = A[M,K](bf16,row) @ Bt[N,K](bf16,row)^T ----------------
// 256x128 tile, 512 threads / 8 waves (wave-tile 64x64), triple-buffered LDS,
// counted vmcnt(3), bijective XCD swizzle (grid%8==0).
template <int MODE>
__global__ __launch_bounds__(512, 2)
void gemm_bt(const u16* __restrict__ A, const u16* __restrict__ Bt,
             int M, int N, int K,
             const float* __restrict__ bias, const float* __restrict__ res,
             void* __restrict__ outp, float oscale, int nm) {
  constexpr int BM = 256, BN = 128;
  constexpr int AccM = 4, AccN = 4;
  __shared__ alignas(16) u16 As[3][BM * 32];   // 16KB per buf
  __shared__ alignas(16) u16 Bs[3][BN * 32];   // 8KB per buf
  const int nwg = gridDim.x;
  const int cpx = nwg >> 3;
  const int wg = (blockIdx.x & 7) * cpx + (blockIdx.x >> 3);
  const int bm = (wg % nm) * BM, bn = (wg / nm) * BN;
  const int tid = threadIdx.x;
  const int lane = tid & 63, w = tid >> 6;
  const int wm = (w >> 1) * 64, wn = (w & 1) * 64;  // 4x2 waves of 64x64
  const int r = lane & 15, g = lane >> 4;
  const int srow = tid >> 2, skk = (tid & 3) * 8;   // 512 thr -> rows 0..127

  f32x4 acc[AccM][AccN];
#pragma unroll
  for (int i = 0; i < AccM; i++)
#pragma unroll
    for (int j = 0; j < AccN; j++) acc[i][j] = (f32x4){0.f, 0.f, 0.f, 0.f};

  const u16* aP = A + (size_t)(bm + srow) * K + skk;
  const u16* bP = Bt + (size_t)(bn + srow) * K + skk;

  auto stage = [&](int kt, int buf) {
    gload_lds16(aP + kt, &As[buf][0] + w * 512);                       // rows 0..127
    gload_lds16(aP + (size_t)128 * K + kt, &As[buf][0] + w * 512 + 4096);  // rows 128..255
    gload_lds16(bP + kt, &Bs[buf][0] + w * 512);                       // rows 0..127
  };
  auto waitL = [&]() {  // 3 loads per stage; keep newest stage in flight
    asm volatile("s_waitcnt vmcnt(3) lgkmcnt(0)" ::: "memory");
  };
  auto compute = [&](int buf) {
    bf16x8 af[AccM], bfr[AccN];
#pragma unroll
    for (int i = 0; i < AccM; i++) af[i] = *(const bf16x8*)(&As[buf][(wm + i * 16 + r) * 32 + g * 8]);
#pragma unroll
    for (int j = 0; j < AccN; j++) bfr[j] = *(const bf16x8*)(&Bs[buf][(wn + j * 16 + r) * 32 + g * 8]);
#pragma unroll
    for (int i = 0; i < AccM; i++)
#pragma unroll
      for (int j = 0; j < AccN; j++) acc[i][j] = MFMA16(af[i], bfr[j], acc[i][j]);
  };

  const int NKT = K / 32;
  stage(0, 0);
  stage(32, 1);
  asm volatile("s_waitcnt vmcnt(3)" ::: "memory");  // buf0 landed
  __builtin_amdgcn_s_barrier();
  __builtin_amdgcn_sched_barrier(0);
  for (int it = 0; it < NKT - 2; ++it) {
    stage((it + 2) * 32, (it + 2) % 3);
    compute(it % 3);
    waitL();  // buf(it+1) landed before barrier
    __builtin_amdgcn_s_barrier();
    __builtin_amdgcn_sched_barrier(0);
  }
  compute((NKT - 2) % 3);
  asm volatile("s_waitcnt vmcnt(0) lgkmcnt(0)" ::: "memory");
  __builtin_amdgcn_s_barrier();
  __builtin_amdgcn_sched_barrier(0);
  compute((NKT - 1) % 3);

#pragma unroll
  for (int i = 0; i < AccM; i++)
#pragma unroll
    for (int j = 0; j < AccN; j++)
#pragma unroll
      for (int t = 0; t < 4; t++) {
        const int mg = bm + wm + i * 16 + g * 4 + t;
        const int ng = bn + wn + j * 16 + r;
        const float v = acc[i][j][t];
        if (MODE == 0) {  // fused QK
          const int which = ng >> 10, col = ng & 1023;
          const int bb = mg >> 11, ssx = mg & 2047, hh = col >> 6, dd = col & 63;
          const float sc = which ? 1.f : oscale;
          ((u16*)outp)[(size_t)which * (TOK * (size_t)DM) +
                       ((size_t)(bb * NH + hh) * SEQ + ssx) * DKK + dd] = f2b(v * sc);
        } else if (MODE == 1) {
          const int hh = mg >> 6, dd = mg & 63, bb = ng >> 11, ssx = ng & 2047;
          ((u16*)outp)[((size_t)(bb * NH + hh) * DKK + dd) * SEQ + ssx] = f2b(v);
        } else if (MODE == 2) {
          ((float*)outp)[(size_t)mg * N + ng] = res[(size_t)mg * N + ng] + v + bias[ng];
        } else {
          const float hv = v + bias[ng];
          ((u16*)outp)[(size_t)mg * N + ng] = f2b(hv > 0.f ? hv : 0.f);
        }
      }
}

// ---------------- flash attention: wave-split-S, barrier-free main loop ----------------
__global__ __launch_bounds__(256, 2)
void attn_kernel(const u16* __restrict__ Q, const u16* __restrict__ Kb,
                 const u16* __restrict__ Vt, const float* __restrict__ mask,
                 u16* __restrict__ outc) {
  const int bid = blockIdx.x;
  const int bh = (bid & 7) * 4 + ((bid >> 3) & 3);  // 4 heads per XCD
  const int qt = bid >> 5;
  const int b = bh >> 4, h = bh & 15;
  const int tid = threadIdx.x, lane = tid & 63, w = tid >> 6;
  const int r = lane & 15, g = lane >> 4;
  const int qbase = qt * 64;
  const u16* Qp = Q + ((size_t)bh * SEQ + qbase) * DKK;
  const u16* Kp = Kb + (size_t)bh * SEQ * DKK;
  const u16* Vp = Vt + (size_t)bh * DKK * SEQ;
  const int wk0 = w * 512;
  const float* mk = mask + b * SEQ + wk0;

  bf16x8 bq0[4], bq1[4];
#pragma unroll
  for (int qf = 0; qf < 4; qf++) {
    bq0[qf] = *(const bf16x8*)(Qp + (size_t)(qf * 16 + r) * DKK + g * 8);
    bq1[qf] = *(const bf16x8*)(Qp + (size_t)(qf * 16 + r) * DKK + 32 + g * 8);
  }

  __shared__ __align__(16) char KV[4][2][8192];
  u16* const K0p = (u16*)&KV[w][0][0];
  u16* const K1p = (u16*)&KV[w][1][0];
  u16* const V0p = (u16*)&KV[w][0][4096];
  u16* const V1p = (u16*)&KV[w][1][4096];
  __shared__ float lrL[4][4][16];

  const int srow8 = lane >> 3;
  const int sgr = (lane & 7) ^ srow8;
  const u16* kS = Kp + (size_t)(wk0 + srow8) * DKK + sgr * 8;
  const u16* vS = Vp + (size_t)(lane >> 2) * SEQ + wk0 + (lane & 3) * 8;

  f32x4 o[4][4];
#pragma unroll
  for (int i = 0; i < 4; i++)
#pragma unroll
    for (int j = 0; j < 4; j++) o[i][j] = (f32x4){0.f, 0.f, 0.f, 0.f};
  float lr[4] = {0.f, 0.f, 0.f, 0.f};
  const int keyr = r & 7;

  gload_lds16(kS, K0p);
  gload_lds16(kS + (size_t)8 * DKK, K0p + 512);
  gload_lds16(kS + (size_t)16 * DKK, K0p + 1024);
  gload_lds16(kS + (size_t)24 * DKK, K0p + 1536);
  gload_lds16(vS, V0p);
  gload_lds16(vS + (size_t)16 * SEQ, V0p + 512);
  gload_lds16(vS + (size_t)32 * SEQ, V0p + 1024);
  gload_lds16(vS + (size_t)48 * SEQ, V0p + 1536);

#define ATILE(T, KP, VP, KPN, VPN, HASNEXT)                                           \
  do {                                                                                \
    const int kk = (T) * 32;                                                          \
    if (HASNEXT) {                                                                    \
      const int nk = kk + 32;                                                         \
      gload_lds16(kS + (size_t)nk * DKK, KPN);                                        \
      gload_lds16(kS + (size_t)(nk + 8) * DKK, KPN + 512);                            \
      gload_lds16(kS + (size_t)(nk + 16) * DKK, KPN + 1024);                          \
      gload_lds16(kS + (size_t)(nk + 24) * DKK, KPN + 1536);                          \
      gload_lds16(vS + nk, VPN);                                                      \
      gload_lds16(vS + (size_t)16 * SEQ + nk, VPN + 512);                             \
      gload_lds16(vS + (size_t)32 * SEQ + nk, VPN + 1024);                            \
      gload_lds16(vS + (size_t)48 * SEQ + nk, VPN + 1536);                            \
      asm volatile("s_waitcnt vmcnt(8)" ::: "memory");                                \
    } else {                                                                          \
      asm volatile("s_waitcnt vmcnt(0)" ::: "memory");                                \
    }                                                                                 \
    const bf16x8 ka0 = *(const bf16x8*)(KP + (size_t)(r)*64 + ((g ^ keyr) << 3));     \
    const bf16x8 ka1 = *(const bf16x8*)(KP + (size_t)(r)*64 + (((g + 4) ^ keyr) << 3));\
    const bf16x8 kb0 = *(const bf16x8*)(KP + (size_t)(16 + r) * 64 + ((g ^ keyr) << 3));\
    const bf16x8 kb1 = *(const bf16x8*)(KP + (size_t)(16 + r) * 64 + (((g + 4) ^ keyr) << 3));\
    f32x4 s0[4], s1[4];                                                               \
    __builtin_amdgcn_s_setprio(1);                                                    \
    _Pragma("unroll")                                                                 \
    for (int qf = 0; qf < 4; qf++) {                                                  \
      f32x4 z = (f32x4){0.f, 0.f, 0.f, 0.f};                                          \
      z = MFMA16(ka0, bq0[qf], z);                                                    \
      z = MFMA16(ka1, bq1[qf], z);                                                    \
      s0[qf] = z;                                                                     \
      f32x4 y = (f32x4){0.f, 0.f, 0.f, 0.f};                                          \
      y = MFMA16(kb0, bq0[qf], y);                                                    \
      y = MFMA16(kb1, bq1[qf], y);                                                    \
      s1[qf] = y;                                                                     \
    }                                                                                 \
    __builtin_amdgcn_s_setprio(0);                                                    \
    const float4 m0 = *(const float4*)(mk + kk + 4 * g);                              \
    const float4 m1 = *(const float4*)(mk + kk + 16 + 4 * g);                         \
    const int ones = (m0.x == 1.f) & (m0.y == 1.f) & (m0.z == 1.f) & (m0.w == 1.f) &  \
                     (m1.x == 1.f) & (m1.y == 1.f) & (m1.z == 1.f) & (m1.w == 1.f);   \
    const bool fastm = __all(ones);                                                   \
    bf16x8 pa[4];                                                                     \
    _Pragma("unroll")                                                                 \
    for (int qf = 0; qf < 4; qf++) {                                                  \
      float p[8];                                                                     \
      if (fastm) {                                                                    \
        p[0] = __builtin_amdgcn_exp2f(s0[qf][0]);                                     \
        p[1] = __builtin_amdgcn_exp2f(s0[qf][1]);                                     \
        p[2] = __builtin_amdgcn_exp2f(s0[qf][2]);                                     \
        p[3] = __builtin_amdgcn_exp2f(s0[qf][3]);                                     \
        p[4] = __builtin_amdgcn_exp2f(s1[qf][0]);                                     \
        p[5] = __builtin_amdgcn_exp2f(s1[qf][1]);                                     \
        p[6] = __builtin_amdgcn_exp2f(s1[qf][2]);                                     \
        p[7] = __builtin_amdgcn_exp2f(s1[qf][3]);                                     \
      } else {                                                                        \
        float pr;                                                                     \
        pr = s0[qf][0] * m0.x; p[0] = (pr == 0.f) ? 0.f : __builtin_amdgcn_exp2f(pr); \
        pr = s0[qf][1] * m0.y; p[1] = (pr == 0.f) ? 0.f : __builtin_amdgcn_exp2f(pr); \
        pr = s0[qf][2] * m0.z; p[2] = (pr == 0.f) ? 0.f : __builtin_amdgcn_exp2f(pr); \
        pr = s0[qf][3] * m0.w; p[3] = (pr == 0.f) ? 0.f : __builtin_amdgcn_exp2f(pr); \
        pr = s1[qf][0] * m1.x; p[4] = (pr == 0.f) ? 0.f : __builtin_amdgcn_exp2f(pr); \
        pr = s1[qf][1] * m1.y; p[5] = (pr == 0.f) ? 0.f : __builtin_amdgcn_exp2f(pr); \
        pr = s1[qf][2] * m1.z; p[6] = (pr == 0.f) ? 0.f : __builtin_amdgcn_exp2f(pr); \
        pr = s1[qf][3] * m1.w; p[7] = (pr == 0.f) ? 0.f : __builtin_amdgcn_exp2f(pr); \
      }                                                                               \
      float rs = ((p[0] + p[1]) + (p[2] + p[3])) + ((p[4] + p[5]) + (p[6] + p[7]));   \
      rs += __shfl_xor(rs, 16);                                                       \
      rs += __shfl_xor(rs, 32);                                                       \
      lr[qf] += rs;                                                                   \
      const unsigned w0 = cvtpk(p[0], p[1]), w1 = cvtpk(p[2], p[3]);                  \
      const unsigned w2 = cvtpk(p[4], p[5]), w3 = cvtpk(p[6], p[7]);                  \
      union { unsigned u[4]; bf16x8 v; } pu;                                          \
      _Pragma("unroll")                                                               \
      for (int c = 0; c < 4; c++) {                                                   \
        const int srcl = r + ((g & 1) * 2 + (c >> 1)) * 16;                           \
        const unsigned lo = __shfl((c & 1) ? w1 : w0, srcl);                          \
        const unsigned hi = __shfl((c & 1) ? w3 : w2, srcl);                          \
        pu.u[c] = (g < 2) ? lo : hi;                                                  \
      }                                                                               \
      pa[qf] = pu.v;                                                                  \
    }                                                                                 \
    __builtin_amdgcn_s_setprio(1);                                                    \
    _Pragma("unroll")                                                                 \
    for (int dc = 0; dc < 4; dc++) {                                                  \
      const bf16x8 bv = *(const bf16x8*)(VP + (size_t)(dc * 16 + r) * 32 + g * 8);    \
      _Pragma("unroll")                                                               \
      for (int qf = 0; qf < 4; qf++) o[qf][dc] = MFMA16(pa[qf], bv, o[qf][dc]);       \
    }                                                                                 \
    __builtin_amdgcn_s_setprio(0);                                                    \
  } while (0)

  for (int tt = 0; tt < 16; tt += 2) {
    ATILE(tt, K0p, V0p, K1p, V1p, true);
    ATILE(tt + 1, K1p, V1p, K0p, V0p, (tt < 14));
  }
#undef ATILE

  float* mo = (float*)&KV[0][0][0];
  float* mw = mo + w * 4096;
#pragma unroll
  for (int qf = 0; qf < 4; qf++)
#pragma unroll
    for (int dc = 0; dc < 4; dc++)
      *(f32x4*)(mw + (size_t)((qf * 4 + dc) * 64 + lane) * 4) = o[qf][dc];
  if (lane < 16) {
#pragma unroll
    for (int qf = 0; qf < 4; qf++) lrL[w][qf][lane] = lr[qf];
  }
  __syncthreads();

  const int qf = w;
  float lq[4];
#pragma unroll
  for (int t = 0; t < 4; t++)
    lq[t] = ((lrL[0][qf][4 * g + t] + lrL[1][qf][4 * g + t]) +
             (lrL[2][qf][4 * g + t] + lrL[3][qf][4 * g + t]));
#pragma unroll
  for (int dc = 0; dc < 4; dc++) {
    f32x4 a0 = *(const f32x4*)(mo + 0 * 4096 + (size_t)((qf * 4 + dc) * 64 + lane) * 4);
    f32x4 a1 = *(const f32x4*)(mo + 1 * 4096 + (size_t)((qf * 4 + dc) * 64 + lane) * 4);
    f32x4 a2 = *(const f32x4*)(mo + 2 * 4096 + (size_t)((qf * 4 + dc) * 64 + lane) * 4);
    f32x4 a3 = *(const f32x4*)(mo + 3 * 4096 + (size_t)((qf * 4 + dc) * 64 + lane) * 4);
#pragma unroll
    for (int t = 0; t < 4; t++) {
      const float val = ((a0[t] + a1[t]) + (a2[t] + a3[t])) / lq[t];
      const int srow_g = qbase + qf * 16 + g * 4 + t;
      outc[((size_t)(b * SEQ + srow_g)) * DM + h * DKK + dc * 16 + r] = f2b(val);
    }
  }
}

extern "C" void kernel_launch(void* const* d_in, const int* in_sizes, int n_in,
                              void* d_out, int out_size, void* d_ws, size_t ws_size,
                              hipStream_t stream) {
  const float* x    = (const float*)d_in[0];
  const float* mask = (const float*)d_in[1];
  const float* Wq   = (const float*)d_in[2];
  const float* Wk   = (const float*)d_in[3];
  const float* Wv   = (const float*)d_in[4];
  const float* Wo   = (const float*)d_in[5];
  const float* bo   = (const float*)d_in[6];
  const float* W1   = (const float*)d_in[7];
  const float* b1   = (const float*)d_in[8];
  const float* W2   = (const float*)d_in[9];
  const float* b2   = (const float*)d_in[10];
  const float* l1a  = (const float*)d_in[11];
  const float* l1b  = (const float*)d_in[12];
  const float* l2a  = (const float*)d_in[13];
  const float* l2b  = (const float*)d_in[14];

  char* wsb = (char*)d_ws;
  u16* Wqkt = (u16*)(wsb + (0ull << 20));
  u16* Wvt  = (u16*)(wsb + (4ull << 20));
  u16* Wot  = (u16*)(wsb + (6ull << 20));
  u16* W1t  = (u16*)(wsb + (8ull << 20));
  u16* W2t  = (u16*)(wsb + (12ull << 20));
  u16* x2   = (u16*)(wsb + (16ull << 20));
  u16* qkb  = (u16*)(wsb + (24ull << 20));
  u16* vtb  = (u16*)(wsb + (40ull << 20));
  float* x1 = (float*)(wsb + (48ull << 20));
  u16* concat = x2;
  u16* x2b = qkb;
  u16* hb  = (u16*)(wsb + (32ull << 20));

  const float qscale = 0.125f * 1.4426950408889634f;

  transpose_all<<<dim3(8192), dim3(32, 8), 0, stream>>>(Wq, Wk, Wv, Wo, W1, W2,
                                                        Wqkt, Wvt, Wot, W1t, W2t);

  ln_kernel<<<TOK, 256, 0, stream>>>(x, l1a, l1b, x2);

  gemm_bt<0><<<dim3(256), 512, 0, stream>>>(
      x2, Wqkt, TOK, 2048, DM, nullptr, nullptr, qkb, qscale, 16);
  gemm_bt<1><<<dim3(128), 512, 0, stream>>>(
      Wvt, x2, DM, TOK, DM, nullptr, nullptr, vtb, 1.0f, 4);

  attn_kernel<<<dim3(1024), 256, 0, stream>>>(qkb, qkb + (size_t)TOK * DM, vtb, mask, concat);

  gemm_bt<2><<<dim3(128), 512, 0, stream>>>(
      concat, Wot, TOK, DM, DM, bo, x, x1, 1.0f, 16);

  ln_kernel<<<TOK, 256, 0, stream>>>(x1, l2a, l2b, x2b);

  gemm_bt<3><<<dim3(256), 512, 0, stream>>>(
      x2b, W1t, TOK, DFF, DM, b1, nullptr, hb, 1.0f, 16);
  gemm_bt<2><<<dim3(128), 512, 0, stream>>>(
      hb, W2t, TOK, DM, DFF, b2, x1, (float*)d_out, 1.0f, 16);
}

// Round 9
// 266.508 us; speedup vs baseline: 1.0475x; 1.0475x over previous
//
#include <hip/hip_runtime.h>
#include <hip/hip_bf16.h>

typedef unsigned short u16;
typedef __attribute__((ext_vector_type(4))) float f32x4;
typedef __attribute__((ext_vector_type(8))) short bf16x8;

#define SEQ 2048
#define DM 1024
#define DKK 64
#define NH 16
#define DFF 2048
#define TOK 4096

#define AS1 __attribute__((address_space(1)))
#define AS3 __attribute__((address_space(3)))

#define MFMA16(a, b, c) __builtin_amdgcn_mfma_f32_16x16x32_bf16((a), (b), (c), 0, 0, 0)

__device__ __forceinline__ u16 f2b(float f) {
  unsigned u = __float_as_uint(f);
  u = u + 0x7fffu + ((u >> 16) & 1u);
  return (u16)(u >> 16);
}

__device__ __forceinline__ unsigned cvtpk(float lo, float hi) {
  unsigned r;
  asm("v_cvt_pk_bf16_f32 %0, %1, %2" : "=v"(r) : "v"(lo), "v"(hi));
  return r;
}

__device__ __forceinline__ void gload_lds16(const u16* g, u16* l) {
  __builtin_amdgcn_global_load_lds((AS1 unsigned*)(size_t)g, (AS3 unsigned*)l, 16, 0, 0);
}

// ---------------- batched weight transpose fp32 [K,N] -> bf16 [N,K] ----------------
__global__ __launch_bounds__(256)
void transpose_all(const float* __restrict__ Wq, const float* __restrict__ Wk,
                   const float* __restrict__ Wv, const float* __restrict__ Wo,
                   const float* __restrict__ W1, const float* __restrict__ W2,
                   u16* __restrict__ Wqkt, u16* __restrict__ Wvt, u16* __restrict__ Wot,
                   u16* __restrict__ W1t, u16* __restrict__ W2t) {
  const int bid = blockIdx.x;
  const float* src;
  u16* dst;
  int K, N, lb;
  if (bid < 1024)      { src = Wq; dst = Wqkt;                 K = 1024; N = 1024; lb = bid; }
  else if (bid < 2048) { src = Wk; dst = Wqkt + (1 << 20);     K = 1024; N = 1024; lb = bid - 1024; }
  else if (bid < 3072) { src = Wv; dst = Wvt;                  K = 1024; N = 1024; lb = bid - 2048; }
  else if (bid < 4096) { src = Wo; dst = Wot;                  K = 1024; N = 1024; lb = bid - 3072; }
  else if (bid < 6144) { src = W1; dst = W1t;                  K = 1024; N = 2048; lb = bid - 4096; }
  else                 { src = W2; dst = W2t;                  K = 2048; N = 1024; lb = bid - 6144; }
  const int nx = N / 32;
  const int n0 = (lb % nx) * 32, k0 = (lb / nx) * 32;
  __shared__ float t[32][33];
  const int tx = threadIdx.x, ty = threadIdx.y;
#pragma unroll
  for (int i = 0; i < 4; i++) {
    int k = ty + i * 8;
    t[k][tx] = src[(size_t)(k0 + k) * N + n0 + tx];
  }
  __syncthreads();
#pragma unroll
  for (int i = 0; i < 4; i++) {
    int n = ty + i * 8;
    dst[(size_t)(n0 + n) * K + k0 + tx] = f2b(t[tx][n]);
  }
}

// ---------------- LayerNorm ----------------
__global__ __launch_bounds__(256)
void ln_kernel(const float* __restrict__ x, const float* __restrict__ alpha,
               const float* __restrict__ beta, u16* __restrict__ out) {
  const int row = blockIdx.x;
  const float4 v = ((const float4*)(x + (size_t)row * DM))[threadIdx.x];
  float s = v.x + v.y + v.z + v.w;
  float q = v.x * v.x + v.y * v.y + v.z * v.z + v.w * v.w;
#pragma unroll
  for (int off = 1; off < 64; off <<= 1) {
    s += __shfl_xor(s, off);
    q += __shfl_xor(q, off);
  }
  __shared__ float ss[4], qq[4];
  const int wid = threadIdx.x >> 6;
  if ((threadIdx.x & 63) == 0) { ss[wid] = s; qq[wid] = q; }
  __syncthreads();
  s = ss[0] + ss[1] + ss[2] + ss[3];
  q = qq[0] + qq[1] + qq[2] + qq[3];
  const float mean = s * (1.f / DM);
  float var = (q - (float)DM * mean * mean) * (1.f / (DM - 1));
  var = fmaxf(var, 0.f);
  const float inv = 1.f / (sqrtf(var) + 1e-6f);
  const float4 a4 = ((const float4*)alpha)[threadIdx.x];
  const float4 b4 = ((const float4*)beta)[threadIdx.x];
  ushort4 o;
  o.x = f2b((v.x - mean) * inv * a4.x + b4.x);
  o.y = f2b((v.y - mean) * inv * a4.y + b4.y);
  o.z = f2b((v.z - mean) * inv * a4.z + b4.z);
  o.w = f2b((v.w - mean) * inv * a4.w + b4.w);
  ((ushort4*)(out + (size_t)row * DM))[threadIdx.x] = o;
}

// ---------------- GEMM (r6 config): triple-buffered LDS, counted vmcnt ----------------
template <int MODE, int BM, int BN>
__global__ __launch_bounds__(256, 4)
void gemm_bt(const u16* __restrict__ A, const u16* __restrict__ Bt,
             int M, int N, int K,
             const float* __restrict__ bias, const float* __restrict__ res,
             void* __restrict__ outp, float oscale) {
  constexpr int AccM = BM / 32;
  constexpr int AccN = BN / 32;
  constexpr int L = (BM == 128 ? 2 : 1) + (BN == 128 ? 2 : 1);
  __shared__ alignas(16) u16 As[3][BM * 32];
  __shared__ alignas(16) u16 Bs[3][BN * 32];
  const int bm = blockIdx.x * BM, bn = blockIdx.y * BN;
  const int tid = threadIdx.x;
  const int lane = tid & 63, w = tid >> 6;
  const int wm = (w >> 1) * (BM / 2), wn = (w & 1) * (BN / 2);
  const int r = lane & 15, g = lane >> 4;
  const int srow = tid >> 2, skk = (tid & 3) * 8;

  f32x4 acc[AccM][AccN];
#pragma unroll
  for (int i = 0; i < AccM; i++)
#pragma unroll
    for (int j = 0; j < AccN; j++) acc[i][j] = (f32x4){0.f, 0.f, 0.f, 0.f};

  const u16* aP = A + (size_t)(bm + srow) * K + skk;
  const u16* bP = Bt + (size_t)(bn + srow) * K + skk;

  auto stage = [&](int kt, int buf) {
    gload_lds16(aP + kt, &As[buf][0] + w * 512);
    if (BM == 128) gload_lds16(aP + (size_t)64 * K + kt, &As[buf][0] + w * 512 + 2048);
    gload_lds16(bP + kt, &Bs[buf][0] + w * 512);
    if (BN == 128) gload_lds16(bP + (size_t)64 * K + kt, &Bs[buf][0] + w * 512 + 2048);
  };
  auto waitL = [&]() {
    if constexpr (L == 4) asm volatile("s_waitcnt vmcnt(4) lgkmcnt(0)" ::: "memory");
    else if constexpr (L == 3) asm volatile("s_waitcnt vmcnt(3) lgkmcnt(0)" ::: "memory");
    else asm volatile("s_waitcnt vmcnt(2) lgkmcnt(0)" ::: "memory");
  };
  auto compute = [&](int buf) {
    bf16x8 af[AccM], bfr[AccN];
#pragma unroll
    for (int i = 0; i < AccM; i++) af[i] = *(const bf16x8*)(&As[buf][(wm + i * 16 + r) * 32 + g * 8]);
#pragma unroll
    for (int j = 0; j < AccN; j++) bfr[j] = *(const bf16x8*)(&Bs[buf][(wn + j * 16 + r) * 32 + g * 8]);
#pragma unroll
    for (int i = 0; i < AccM; i++)
#pragma unroll
      for (int j = 0; j < AccN; j++) acc[i][j] = MFMA16(af[i], bfr[j], acc[i][j]);
  };

  const int NKT = K / 32;
  stage(0, 0);
  stage(32, 1);
  waitL();
  __builtin_amdgcn_s_barrier();
  __builtin_amdgcn_sched_barrier(0);
  for (int it = 0; it < NKT - 2; ++it) {
    stage((it + 2) * 32, (it + 2) % 3);
    compute(it % 3);
    waitL();
    __builtin_amdgcn_s_barrier();
    __builtin_amdgcn_sched_barrier(0);
  }
  compute((NKT - 2) % 3);
  asm volatile("s_waitcnt vmcnt(0) lgkmcnt(0)" ::: "memory");
  __builtin_amdgcn_s_barrier();
  __builtin_amdgcn_sched_barrier(0);
  compute((NKT - 1) % 3);

#pragma unroll
  for (int i = 0; i < AccM; i++)
#pragma unroll
    for (int j = 0; j < AccN; j++)
#pragma unroll
      for (int t = 0; t < 4; t++) {
        const int mg = bm + wm + i * 16 + g * 4 + t;
        const int ng = bn + wn + j * 16 + r;
        const float v = acc[i][j][t];
        if (MODE == 0) {  // fused QK
          const int which = ng >> 10, col = ng & 1023;
          const int bb = mg >> 11, ssx = mg & 2047, hh = col >> 6, dd = col & 63;
          const float sc = which ? 1.f : oscale;
          ((u16*)outp)[(size_t)which * (TOK * (size_t)DM) +
                       ((size_t)(bb * NH + hh) * SEQ + ssx) * DKK + dd] = f2b(v * sc);
        } else if (MODE == 1) {
          const int hh = mg >> 6, dd = mg & 63, bb = ng >> 11, ssx = ng & 2047;
          ((u16*)outp)[((size_t)(bb * NH + hh) * DKK + dd) * SEQ + ssx] = f2b(v);
        } else if (MODE == 2) {
          ((float*)outp)[(size_t)mg * N + ng] = res[(size_t)mg * N + ng] + v + bias[ng];
        } else {
          const float hv = v + bias[ng];
          ((u16*)outp)[(size_t)mg * N + ng] = f2b(hv > 0.f ? hv : 0.f);
        }
      }
}

// ---------------- flash attention v9: wave-split-S, barrier-free, 48KB LDS ----------------
// K: global_load_lds double-buffer (pre-swizzled src). V: T14 reg-staged single buffer
// (loads issued one iter early; vmcnt(0)+ds_write AFTER PV reads old tile; in-order DS).
__global__ __launch_bounds__(256, 4)
void attn_kernel(const u16* __restrict__ Q, const u16* __restrict__ Kb,
                 const u16* __restrict__ Vt, const float* __restrict__ mask,
                 u16* __restrict__ outc) {
  const int bid = blockIdx.x;
  const int bh = (bid & 7) * 4 + ((bid >> 3) & 3);  // 4 heads per XCD
  const int qt = bid >> 5;
  const int b = bh >> 4, h = bh & 15;
  const int tid = threadIdx.x, lane = tid & 63, w = tid >> 6;
  const int r = lane & 15, g = lane >> 4;
  const int qbase = qt * 64;
  const u16* Qp = Q + ((size_t)bh * SEQ + qbase) * DKK;
  const u16* Kp = Kb + (size_t)bh * SEQ * DKK;
  const u16* Vp = Vt + (size_t)bh * DKK * SEQ;
  const int wk0 = w * 512;
  const float* mk = mask + b * SEQ + wk0;

  bf16x8 bq0[4], bq1[4];
#pragma unroll
  for (int qf = 0; qf < 4; qf++) {
    bq0[qf] = *(const bf16x8*)(Qp + (size_t)(qf * 16 + r) * DKK + g * 8);
    bq1[qf] = *(const bf16x8*)(Qp + (size_t)(qf * 16 + r) * DKK + 32 + g * 8);
  }

  __shared__ __align__(16) u16 Ks[4][2][32 * 64];  // 32KB: per-wave K double-buffer
  __shared__ __align__(16) u16 Vs[4][64 * 32];     // 16KB: per-wave V single buffer
  __shared__ float lrL[4][4][16];

  const int srow8 = lane >> 3;
  const int sgr = (lane & 7) ^ srow8;
  const u16* kS = Kp + (size_t)(wk0 + srow8) * DKK + sgr * 8;
  const u16* vS = Vp + (size_t)(lane >> 2) * SEQ + wk0 + (lane & 3) * 8;
  u16* const Kw0 = &Ks[w][0][0];
  u16* const Kw1 = &Ks[w][1][0];
  u16* const Vw = &Vs[w][0];
  u16* const vD = Vw + (lane >> 2) * 32 + (lane & 3) * 8;

  f32x4 o[4][4];
#pragma unroll
  for (int i = 0; i < 4; i++)
#pragma unroll
    for (int j = 0; j < 4; j++) o[i][j] = (f32x4){0.f, 0.f, 0.f, 0.f};
  float lr[4] = {0.f, 0.f, 0.f, 0.f};
  const int keyr = r & 7;

  // prologue: K(0) -> Kw0 ; V(0) -> regs -> Vw ; issue K(1), V(1)
  gload_lds16(kS, Kw0);
  gload_lds16(kS + (size_t)8 * DKK, Kw0 + 512);
  gload_lds16(kS + (size_t)16 * DKK, Kw0 + 1024);
  gload_lds16(kS + (size_t)24 * DKK, Kw0 + 1536);
  int4 vst0 = *(const int4*)(vS);
  int4 vst1 = *(const int4*)(vS + (size_t)16 * SEQ);
  int4 vst2 = *(const int4*)(vS + (size_t)32 * SEQ);
  int4 vst3 = *(const int4*)(vS + (size_t)48 * SEQ);
  asm volatile("s_waitcnt vmcnt(0)" ::: "memory");
  *(int4*)(vD) = vst0;
  *(int4*)(vD + 512) = vst1;
  *(int4*)(vD + 1024) = vst2;
  *(int4*)(vD + 1536) = vst3;
  gload_lds16(kS + (size_t)32 * DKK, Kw1);
  gload_lds16(kS + (size_t)40 * DKK, Kw1 + 512);
  gload_lds16(kS + (size_t)48 * DKK, Kw1 + 1024);
  gload_lds16(kS + (size_t)56 * DKK, Kw1 + 1536);
  vst0 = *(const int4*)(vS + 32);
  vst1 = *(const int4*)(vS + (size_t)16 * SEQ + 32);
  vst2 = *(const int4*)(vS + (size_t)32 * SEQ + 32);
  vst3 = *(const int4*)(vS + (size_t)48 * SEQ + 32);

#define ASTEP(I, KCUR)                                                                \
  do {                                                                                \
    const int kk = (I) * 32;                                                          \
    const bf16x8 ka0 = *(const bf16x8*)(KCUR + r * 64 + ((g ^ keyr) << 3));           \
    const bf16x8 ka1 = *(const bf16x8*)(KCUR + r * 64 + (((g + 4) ^ keyr) << 3));     \
    const bf16x8 kb0 = *(const bf16x8*)(KCUR + (16 + r) * 64 + ((g ^ keyr) << 3));    \
    const bf16x8 kb1 = *(const bf16x8*)(KCUR + (16 + r) * 64 + (((g + 4) ^ keyr) << 3)); \
    f32x4 s0[4], s1[4];                                                               \
    __builtin_amdgcn_s_setprio(1);                                                    \
    _Pragma("unroll")                                                                 \
    for (int qf = 0; qf < 4; qf++) {                                                  \
      f32x4 z = (f32x4){0.f, 0.f, 0.f, 0.f};                                          \
      z = MFMA16(ka0, bq0[qf], z);                                                    \
      z = MFMA16(ka1, bq1[qf], z);                                                    \
      s0[qf] = z;                                                                     \
      f32x4 y = (f32x4){0.f, 0.f, 0.f, 0.f};                                          \
      y = MFMA16(kb0, bq0[qf], y);                                                    \
      y = MFMA16(kb1, bq1[qf], y);                                                    \
      s1[qf] = y;                                                                     \
    }                                                                                 \
    __builtin_amdgcn_s_setprio(0);                                                    \
    const float4 m0 = *(const float4*)(mk + kk + 4 * g);                              \
    const float4 m1 = *(const float4*)(mk + kk + 16 + 4 * g);                         \
    const int ones = (m0.x == 1.f) & (m0.y == 1.f) & (m0.z == 1.f) & (m0.w == 1.f) &  \
                     (m1.x == 1.f) & (m1.y == 1.f) & (m1.z == 1.f) & (m1.w == 1.f);   \
    const bool fastm = __all(ones);                                                   \
    bf16x8 pa[4];                                                                     \
    _Pragma("unroll")                                                                 \
    for (int qf = 0; qf < 4; qf++) {                                                  \
      float p[8];                                                                     \
      if (fastm) {                                                                    \
        p[0] = __builtin_amdgcn_exp2f(s0[qf][0]);                                     \
        p[1] = __builtin_amdgcn_exp2f(s0[qf][1]);                                     \
        p[2] = __builtin_amdgcn_exp2f(s0[qf][2]);                                     \
        p[3] = __builtin_amdgcn_exp2f(s0[qf][3]);                                     \
        p[4] = __builtin_amdgcn_exp2f(s1[qf][0]);                                     \
        p[5] = __builtin_amdgcn_exp2f(s1[qf][1]);                                     \
        p[6] = __builtin_amdgcn_exp2f(s1[qf][2]);                                     \
        p[7] = __builtin_amdgcn_exp2f(s1[qf][3]);                                     \
      } else {                                                                        \
        float pr;                                                                     \
        pr = s0[qf][0] * m0.x; p[0] = (pr == 0.f) ? 0.f : __builtin_amdgcn_exp2f(pr); \
        pr = s0[qf][1] * m0.y; p[1] = (pr == 0.f) ? 0.f : __builtin_amdgcn_exp2f(pr); \
        pr = s0[qf][2] * m0.z; p[2] = (pr == 0.f) ? 0.f : __builtin_amdgcn_exp2f(pr); \
        pr = s0[qf][3] * m0.w; p[3] = (pr == 0.f) ? 0.f : __builtin_amdgcn_exp2f(pr); \
        pr = s1[qf][0] * m1.x; p[4] = (pr == 0.f) ? 0.f : __builtin_amdgcn_exp2f(pr); \
        pr = s1[qf][1] * m1.y; p[5] = (pr == 0.f) ? 0.f : __builtin_amdgcn_exp2f(pr); \
        pr = s1[qf][2] * m1.z; p[6] = (pr == 0.f) ? 0.f : __builtin_amdgcn_exp2f(pr); \
        pr = s1[qf][3] * m1.w; p[7] = (pr == 0.f) ? 0.f : __builtin_amdgcn_exp2f(pr); \
      }                                                                               \
      float rs = ((p[0] + p[1]) + (p[2] + p[3])) + ((p[4] + p[5]) + (p[6] + p[7]));   \
      rs += __shfl_xor(rs, 16);                                                       \
      rs += __shfl_xor(rs, 32);                                                       \
      lr[qf] += rs;                                                                   \
      const unsigned w0 = cvtpk(p[0], p[1]), w1 = cvtpk(p[2], p[3]);                  \
      const unsigned w2 = cvtpk(p[4], p[5]), w3 = cvtpk(p[6], p[7]);                  \
      union { unsigned u[4]; bf16x8 v; } pu;                                          \
      _Pragma("unroll")                                                               \
      for (int c = 0; c < 4; c++) {                                                   \
        const int srcl = r + ((g & 1) * 2 + (c >> 1)) * 16;                           \
        const unsigned lo = __shfl((c & 1) ? w1 : w0, srcl);                          \
        const unsigned hi = __shfl((c & 1) ? w3 : w2, srcl);                          \
        pu.u[c] = (g < 2) ? lo : hi;                                                  \
      }                                                                               \
      pa[qf] = pu.v;                                                                  \
    }                                                                                 \
    __builtin_amdgcn_s_setprio(1);                                                    \
    _Pragma("unroll")                                                                 \
    for (int dc = 0; dc < 4; dc++) {                                                  \
      const bf16x8 bv = *(const bf16x8*)(Vw + (dc * 16 + r) * 32 + g * 8);            \
      _Pragma("unroll")                                                               \
      for (int qf = 0; qf < 4; qf++) o[qf][dc] = MFMA16(pa[qf], bv, o[qf][dc]);       \
    }                                                                                 \
    __builtin_amdgcn_s_setprio(0);                                                    \
    if ((I) < 15) {                                                                   \
      asm volatile("s_waitcnt vmcnt(0)" ::: "memory");                                \
      *(int4*)(vD) = vst0;                                                            \
      *(int4*)(vD + 512) = vst1;                                                      \
      *(int4*)(vD + 1024) = vst2;                                                     \
      *(int4*)(vD + 1536) = vst3;                                                     \
      if ((I) < 14) {                                                                 \
        const int nk = kk + 64;                                                       \
        gload_lds16(kS + (size_t)nk * DKK, KCUR);                                     \
        gload_lds16(kS + (size_t)(nk + 8) * DKK, KCUR + 512);                         \
        gload_lds16(kS + (size_t)(nk + 16) * DKK, KCUR + 1024);                       \
        gload_lds16(kS + (size_t)(nk + 24) * DKK, KCUR + 1536);                       \
        vst0 = *(const int4*)(vS + nk);                                               \
        vst1 = *(const int4*)(vS + (size_t)16 * SEQ + nk);                            \
        vst2 = *(const int4*)(vS + (size_t)32 * SEQ + nk);                            \
        vst3 = *(const int4*)(vS + (size_t)48 * SEQ + nk);                            \
      }                                                                               \
    }                                                                                 \
  } while (0)

  for (int tt = 0; tt < 16; tt += 2) {
    ASTEP(tt, Kw0);
    ASTEP(tt + 1, Kw1);
  }
#undef ASTEP

  // ---- two-pass cross-wave merge (32KB scratch in Ks region) ----
  if (lane < 16) {
#pragma unroll
    for (int qf = 0; qf < 4; qf++) lrL[w][qf][lane] = lr[qf];
  }
  float* mo = (float*)&Ks[0][0][0];
  float* mw = mo + w * 2048;
#pragma unroll
  for (int qf = 0; qf < 2; qf++)
#pragma unroll
    for (int dc = 0; dc < 4; dc++)
      *(f32x4*)(mw + (size_t)((qf * 4 + dc) * 64 + lane) * 4) = o[qf][dc];
  __syncthreads();
  if (w < 2) {
    const int qf = w;
    float lq[4];
#pragma unroll
    for (int t = 0; t < 4; t++)
      lq[t] = ((lrL[0][qf][4 * g + t] + lrL[1][qf][4 * g + t]) +
               (lrL[2][qf][4 * g + t] + lrL[3][qf][4 * g + t]));
#pragma unroll
    for (int dc = 0; dc < 4; dc++) {
      f32x4 a0 = *(const f32x4*)(mo + 0 * 2048 + (size_t)((qf * 4 + dc) * 64 + lane) * 4);
      f32x4 a1 = *(const f32x4*)(mo + 1 * 2048 + (size_t)((qf * 4 + dc) * 64 + lane) * 4);
      f32x4 a2 = *(const f32x4*)(mo + 2 * 2048 + (size_t)((qf * 4 + dc) * 64 + lane) * 4);
      f32x4 a3 = *(const f32x4*)(mo + 3 * 2048 + (size_t)((qf * 4 + dc) * 64 + lane) * 4);
#pragma unroll
      for (int t = 0; t < 4; t++) {
        const float val = ((a0[t] + a1[t]) + (a2[t] + a3[t])) / lq[t];
        const int srow_g = qbase + qf * 16 + g * 4 + t;
        outc[((size_t)(b * SEQ + srow_g)) * DM + h * DKK + dc * 16 + r] = f2b(val);
      }
    }
  }
  __syncthreads();
#pragma unroll
  for (int qf = 2; qf < 4; qf++)
#pragma unroll
    for (int dc = 0; dc < 4; dc++)
      *(f32x4*)(mw + (size_t)(((qf - 2) * 4 + dc) * 64 + lane) * 4) = o[qf][dc];
  __syncthreads();
  if (w >= 2) {
    const int qf = w;
    float lq[4];
#pragma unroll
    for (int t = 0; t < 4; t++)
      lq[t] = ((lrL[0][qf][4 * g + t] + lrL[1][qf][4 * g + t]) +
               (lrL[2][qf][4 * g + t] + lrL[3][qf][4 * g + t]));
#pragma unroll
    for (int dc = 0; dc < 4; dc++) {
      f32x4 a0 = *(const f32x4*)(mo + 0 * 2048 + (size_t)(((qf - 2) * 4 + dc) * 64 + lane) * 4);
      f32x4 a1 = *(const f32x4*)(mo + 1 * 2048 + (size_t)(((qf - 2) * 4 + dc) * 64 + lane) * 4);
      f32x4 a2 = *(const f32x4*)(mo + 2 * 2048 + (size_t)(((qf - 2) * 4 + dc) * 64 + lane) * 4);
      f32x4 a3 = *(const f32x4*)(mo + 3 * 2048 + (size_t)(((qf - 2) * 4 + dc) * 64 + lane) * 4);
#pragma unroll
      for (int t = 0; t < 4; t++) {
        const float val = ((a0[t] + a1[t]) + (a2[t] + a3[t])) / lq[t];
        const int srow_g = qbase + qf * 16 + g * 4 + t;
        outc[((size_t)(b * SEQ + srow_g)) * DM + h * DKK + dc * 16 + r] = f2b(val);
      }
    }
  }
}

extern "C" void kernel_launch(void* const* d_in, const int* in_sizes, int n_in,
                              void* d_out, int out_size, void* d_ws, size_t ws_size,
                              hipStream_t stream) {
  const float* x    = (const float*)d_in[0];
  const float* mask = (const float*)d_in[1];
  const float* Wq   = (const float*)d_in[2];
  const float* Wk   = (const float*)d_in[3];
  const float* Wv   = (const float*)d_in[4];
  const float* Wo   = (const float*)d_in[5];
  const float* bo   = (const float*)d_in[6];
  const float* W1   = (const float*)d_in[7];
  const float* b1   = (const float*)d_in[8];
  const float* W2   = (const float*)d_in[9];
  const float* b2   = (const float*)d_in[10];
  const float* l1a  = (const float*)d_in[11];
  const float* l1b  = (const float*)d_in[12];
  const float* l2a  = (const float*)d_in[13];
  const float* l2b  = (const float*)d_in[14];

  char* wsb = (char*)d_ws;
  u16* Wqkt = (u16*)(wsb + (0ull << 20));
  u16* Wvt  = (u16*)(wsb + (4ull << 20));
  u16* Wot  = (u16*)(wsb + (6ull << 20));
  u16* W1t  = (u16*)(wsb + (8ull << 20));
  u16* W2t  = (u16*)(wsb + (12ull << 20));
  u16* x2   = (u16*)(wsb + (16ull << 20));
  u16* qkb  = (u16*)(wsb + (24ull << 20));
  u16* vtb  = (u16*)(wsb + (40ull << 20));
  float* x1 = (float*)(wsb + (48ull << 20));
  u16* concat = x2;
  u16* x2b = qkb;
  u16* hb  = (u16*)(wsb + (32ull << 20));

  const float qscale = 0.125f * 1.4426950408889634f;

  transpose_all<<<dim3(8192), dim3(32, 8), 0, stream>>>(Wq, Wk, Wv, Wo, W1, W2,
                                                        Wqkt, Wvt, Wot, W1t, W2t);

  ln_kernel<<<TOK, 256, 0, stream>>>(x, l1a, l1b, x2);

  gemm_bt<0, 64, 128><<<dim3(TOK / 64, 2048 / 128), 256, 0, stream>>>(
      x2, Wqkt, TOK, 2048, DM, nullptr, nullptr, qkb, qscale);
  gemm_bt<1, 64, 64><<<dim3(DM / 64, TOK / 64), 256, 0, stream>>>(
      Wvt, x2, DM, TOK, DM, nullptr, nullptr, vtb, 1.0f);

  attn_kernel<<<dim3(1024), 256, 0, stream>>>(qkb, qkb + (size_t)TOK * DM, vtb, mask, concat);

  gemm_bt<2, 64, 64><<<dim3(TOK / 64, DM / 64), 256, 0, stream>>>(
      concat, Wot, TOK, DM, DM, bo, x, x1, 1.0f);

  ln_kernel<<<TOK, 256, 0, stream>>>(x1, l2a, l2b, x2b);

  gemm_bt<3, 64, 128><<<dim3(TOK / 64, DFF / 128), 256, 0, stream>>>(
      x2b, W1t, TOK, DFF, DM, b1, nullptr, hb, 1.0f);
  gemm_bt<2, 64, 64><<<dim3(TOK / 64, DM / 64), 256, 0, stream>>>(
      hb, W2t, TOK, DM, DFF, b2, x1, (float*)d_out, 1.0f);
}

// Round 10
// 218.858 us; speedup vs baseline: 1.2756x; 1.2177x over previous
//
#include <hip/hip_runtime.h>
#include <hip/hip_bf16.h>

typedef unsigned short u16;
typedef __attribute__((ext_vector_type(4))) float f32x4;
typedef __attribute__((ext_vector_type(8))) short bf16x8;

#define SEQ 2048
#define DM 1024
#define DKK 64
#define NH 16
#define DFF 2048
#define TOK 4096

#define AS1 __attribute__((address_space(1)))
#define AS3 __attribute__((address_space(3)))

#define MFMA16(a, b, c) __builtin_amdgcn_mfma_f32_16x16x32_bf16((a), (b), (c), 0, 0, 0)

__device__ __forceinline__ u16 f2b(float f) {
  unsigned u = __float_as_uint(f);
  u = u + 0x7fffu + ((u >> 16) & 1u);
  return (u16)(u >> 16);
}

__device__ __forceinline__ unsigned cvtpk(float lo, float hi) {
  unsigned r;
  asm("v_cvt_pk_bf16_f32 %0, %1, %2" : "=v"(r) : "v"(lo), "v"(hi));
  return r;
}

__device__ __forceinline__ void gload_lds16(const u16* g, u16* l) {
  __builtin_amdgcn_global_load_lds((AS1 unsigned*)(size_t)g, (AS3 unsigned*)l, 16, 0, 0);
}

// ------- fused prep: 6 weight transposes (fp32 [K,N] -> bf16 [N,K]) + LayerNorm1 -------
__global__ __launch_bounds__(256)
void prep_all(const float* __restrict__ Wq, const float* __restrict__ Wk,
              const float* __restrict__ Wv, const float* __restrict__ Wo,
              const float* __restrict__ W1, const float* __restrict__ W2,
              u16* __restrict__ Wqkt, u16* __restrict__ Wvt, u16* __restrict__ Wot,
              u16* __restrict__ W1t, u16* __restrict__ W2t,
              const float* __restrict__ x, const float* __restrict__ alpha,
              const float* __restrict__ beta, u16* __restrict__ xout) {
  __shared__ float t[32][33];
  const int bid = blockIdx.x;
  const int tid = threadIdx.x;
  if (bid < 8192) {  // transpose path
    const float* src;
    u16* dst;
    int K, N, lb;
    if (bid < 1024)      { src = Wq; dst = Wqkt;             K = 1024; N = 1024; lb = bid; }
    else if (bid < 2048) { src = Wk; dst = Wqkt + (1 << 20); K = 1024; N = 1024; lb = bid - 1024; }
    else if (bid < 3072) { src = Wv; dst = Wvt;              K = 1024; N = 1024; lb = bid - 2048; }
    else if (bid < 4096) { src = Wo; dst = Wot;              K = 1024; N = 1024; lb = bid - 3072; }
    else if (bid < 6144) { src = W1; dst = W1t;              K = 1024; N = 2048; lb = bid - 4096; }
    else                 { src = W2; dst = W2t;              K = 2048; N = 1024; lb = bid - 6144; }
    const int nx = N / 32;
    const int n0 = (lb % nx) * 32, k0 = (lb / nx) * 32;
    const int tx = tid & 31, ty = tid >> 5;
#pragma unroll
    for (int i = 0; i < 4; i++) {
      int k = ty + i * 8;
      t[k][tx] = src[(size_t)(k0 + k) * N + n0 + tx];
    }
    __syncthreads();
#pragma unroll
    for (int i = 0; i < 4; i++) {
      int n = ty + i * 8;
      dst[(size_t)(n0 + n) * K + k0 + tx] = f2b(t[tx][n]);
    }
  } else {  // LayerNorm1 path
    const int row = bid - 8192;
    const float4 v = ((const float4*)(x + (size_t)row * DM))[tid];
    float s = v.x + v.y + v.z + v.w;
    float q = v.x * v.x + v.y * v.y + v.z * v.z + v.w * v.w;
#pragma unroll
    for (int off = 1; off < 64; off <<= 1) {
      s += __shfl_xor(s, off);
      q += __shfl_xor(q, off);
    }
    float* ss = &t[0][0];
    float* qq = &t[0][8];
    const int wid = tid >> 6;
    if ((tid & 63) == 0) { ss[wid] = s; qq[wid] = q; }
    __syncthreads();
    s = ss[0] + ss[1] + ss[2] + ss[3];
    q = qq[0] + qq[1] + qq[2] + qq[3];
    const float mean = s * (1.f / DM);
    float var = (q - (float)DM * mean * mean) * (1.f / (DM - 1));
    var = fmaxf(var, 0.f);
    const float inv = 1.f / (sqrtf(var) + 1e-6f);
    const float4 a4 = ((const float4*)alpha)[tid];
    const float4 b4 = ((const float4*)beta)[tid];
    ushort4 o;
    o.x = f2b((v.x - mean) * inv * a4.x + b4.x);
    o.y = f2b((v.y - mean) * inv * a4.y + b4.y);
    o.z = f2b((v.z - mean) * inv * a4.z + b4.z);
    o.w = f2b((v.w - mean) * inv * a4.w + b4.w);
    ((ushort4*)(xout + (size_t)row * DM))[tid] = o;
  }
}

// ---------------- LayerNorm (standalone, for LN2) ----------------
__global__ __launch_bounds__(256)
void ln_kernel(const float* __restrict__ x, const float* __restrict__ alpha,
               const float* __restrict__ beta, u16* __restrict__ out) {
  const int row = blockIdx.x;
  const float4 v = ((const float4*)(x + (size_t)row * DM))[threadIdx.x];
  float s = v.x + v.y + v.z + v.w;
  float q = v.x * v.x + v.y * v.y + v.z * v.z + v.w * v.w;
#pragma unroll
  for (int off = 1; off < 64; off <<= 1) {
    s += __shfl_xor(s, off);
    q += __shfl_xor(q, off);
  }
  __shared__ float ss[4], qq[4];
  const int wid = threadIdx.x >> 6;
  if ((threadIdx.x & 63) == 0) { ss[wid] = s; qq[wid] = q; }
  __syncthreads();
  s = ss[0] + ss[1] + ss[2] + ss[3];
  q = qq[0] + qq[1] + qq[2] + qq[3];
  const float mean = s * (1.f / DM);
  float var = (q - (float)DM * mean * mean) * (1.f / (DM - 1));
  var = fmaxf(var, 0.f);
  const float inv = 1.f / (sqrtf(var) + 1e-6f);
  const float4 a4 = ((const float4*)alpha)[threadIdx.x];
  const float4 b4 = ((const float4*)beta)[threadIdx.x];
  ushort4 o;
  o.x = f2b((v.x - mean) * inv * a4.x + b4.x);
  o.y = f2b((v.y - mean) * inv * a4.y + b4.y);
  o.z = f2b((v.z - mean) * inv * a4.z + b4.z);
  o.w = f2b((v.w - mean) * inv * a4.w + b4.w);
  ((ushort4*)(out + (size_t)row * DM))[threadIdx.x] = o;
}

// ---------------- fused QKV GEMM: QK blocks (mode 0) + V blocks (mode 1) ----------------
// 64x128 tile, triple-buffered LDS, counted vmcnt — r6-proven body, runtime block branch.
__global__ __launch_bounds__(256, 4)
void qkv_gemm(const u16* __restrict__ x2, const u16* __restrict__ Wqkt,
              const u16* __restrict__ Wvt,
              u16* __restrict__ qkb, u16* __restrict__ vtb, float oscale) {
  constexpr int BM = 64, BN = 128, AccM = 2, AccN = 4;
  __shared__ alignas(16) u16 As[3][BM * 32];
  __shared__ alignas(16) u16 Bs[3][BN * 32];
  const int bid = blockIdx.x;
  const int K = DM;
  const u16* A;
  const u16* Bt;
  int bm, bn, mode;
  if (bid < 1024) {  // QK: C[4096 x 2048]
    mode = 0; A = x2; Bt = Wqkt;
    bm = (bid & 63) * BM; bn = (bid >> 6) * BN;
  } else {           // V: C[1024 x 4096] = Wvt @ x2^T
    mode = 1; A = Wvt; Bt = x2;
    const int lb = bid - 1024;
    bm = (lb & 15) * BM; bn = (lb >> 4) * BN;
  }
  const int tid = threadIdx.x;
  const int lane = tid & 63, w = tid >> 6;
  const int wm = (w >> 1) * (BM / 2), wn = (w & 1) * (BN / 2);
  const int r = lane & 15, g = lane >> 4;
  const int srow = tid >> 2, skk = (tid & 3) * 8;

  f32x4 acc[AccM][AccN];
#pragma unroll
  for (int i = 0; i < AccM; i++)
#pragma unroll
    for (int j = 0; j < AccN; j++) acc[i][j] = (f32x4){0.f, 0.f, 0.f, 0.f};

  const u16* aP = A + (size_t)(bm + srow) * K + skk;
  const u16* bP = Bt + (size_t)(bn + srow) * K + skk;

  auto stage = [&](int kt, int buf) {
    gload_lds16(aP + kt, &As[buf][0] + w * 512);
    gload_lds16(bP + kt, &Bs[buf][0] + w * 512);
    gload_lds16(bP + (size_t)64 * K + kt, &Bs[buf][0] + w * 512 + 2048);
  };
  auto waitL = [&]() { asm volatile("s_waitcnt vmcnt(3) lgkmcnt(0)" ::: "memory"); };
  auto compute = [&](int buf) {
    bf16x8 af[AccM], bfr[AccN];
#pragma unroll
    for (int i = 0; i < AccM; i++) af[i] = *(const bf16x8*)(&As[buf][(wm + i * 16 + r) * 32 + g * 8]);
#pragma unroll
    for (int j = 0; j < AccN; j++) bfr[j] = *(const bf16x8*)(&Bs[buf][(wn + j * 16 + r) * 32 + g * 8]);
#pragma unroll
    for (int i = 0; i < AccM; i++)
#pragma unroll
      for (int j = 0; j < AccN; j++) acc[i][j] = MFMA16(af[i], bfr[j], acc[i][j]);
  };

  const int NKT = K / 32;
  stage(0, 0);
  stage(32, 1);
  waitL();
  __builtin_amdgcn_s_barrier();
  __builtin_amdgcn_sched_barrier(0);
  for (int it = 0; it < NKT - 2; ++it) {
    stage((it + 2) * 32, (it + 2) % 3);
    compute(it % 3);
    waitL();
    __builtin_amdgcn_s_barrier();
    __builtin_amdgcn_sched_barrier(0);
  }
  compute((NKT - 2) % 3);
  asm volatile("s_waitcnt vmcnt(0) lgkmcnt(0)" ::: "memory");
  __builtin_amdgcn_s_barrier();
  __builtin_amdgcn_sched_barrier(0);
  compute((NKT - 1) % 3);

#pragma unroll
  for (int i = 0; i < AccM; i++)
#pragma unroll
    for (int j = 0; j < AccN; j++)
#pragma unroll
      for (int t = 0; t < 4; t++) {
        const int mg = bm + wm + i * 16 + g * 4 + t;
        const int ng = bn + wn + j * 16 + r;
        const float v = acc[i][j][t];
        if (mode == 0) {  // Q (scaled) / K scatter to [B,H,S,dk]
          const int which = ng >> 10, col = ng & 1023;
          const int bb = mg >> 11, ssx = mg & 2047, hh = col >> 6, dd = col & 63;
          const float sc = which ? 1.f : oscale;
          qkb[(size_t)which * (TOK * (size_t)DM) +
              ((size_t)(bb * NH + hh) * SEQ + ssx) * DKK + dd] = f2b(v * sc);
        } else {          // V^T scatter to [B,H,dk,S]
          const int hh = mg >> 6, dd = mg & 63, bb = ng >> 11, ssx = ng & 2047;
          vtb[((size_t)(bb * NH + hh) * DKK + dd) * SEQ + ssx] = f2b(v);
        }
      }
}

// ---------------- GEMM (r6 config): triple-buffered LDS, counted vmcnt ----------------
// MODE 2: fp32 out = res + acc + bias;  MODE 3: bf16 out = relu(acc + bias)
template <int MODE, int BM, int BN>
__global__ __launch_bounds__(256, 4)
void gemm_bt(const u16* __restrict__ A, const u16* __restrict__ Bt,
             int M, int N, int K,
             const float* __restrict__ bias, const float* __restrict__ res,
             void* __restrict__ outp) {
  constexpr int AccM = BM / 32;
  constexpr int AccN = BN / 32;
  constexpr int L = (BM == 128 ? 2 : 1) + (BN == 128 ? 2 : 1);
  __shared__ alignas(16) u16 As[3][BM * 32];
  __shared__ alignas(16) u16 Bs[3][BN * 32];
  const int bm = blockIdx.x * BM, bn = blockIdx.y * BN;
  const int tid = threadIdx.x;
  const int lane = tid & 63, w = tid >> 6;
  const int wm = (w >> 1) * (BM / 2), wn = (w & 1) * (BN / 2);
  const int r = lane & 15, g = lane >> 4;
  const int srow = tid >> 2, skk = (tid & 3) * 8;

  f32x4 acc[AccM][AccN];
#pragma unroll
  for (int i = 0; i < AccM; i++)
#pragma unroll
    for (int j = 0; j < AccN; j++) acc[i][j] = (f32x4){0.f, 0.f, 0.f, 0.f};

  const u16* aP = A + (size_t)(bm + srow) * K + skk;
  const u16* bP = Bt + (size_t)(bn + srow) * K + skk;

  auto stage = [&](int kt, int buf) {
    gload_lds16(aP + kt, &As[buf][0] + w * 512);
    if (BM == 128) gload_lds16(aP + (size_t)64 * K + kt, &As[buf][0] + w * 512 + 2048);
    gload_lds16(bP + kt, &Bs[buf][0] + w * 512);
    if (BN == 128) gload_lds16(bP + (size_t)64 * K + kt, &Bs[buf][0] + w * 512 + 2048);
  };
  auto waitL = [&]() {
    if constexpr (L == 4) asm volatile("s_waitcnt vmcnt(4) lgkmcnt(0)" ::: "memory");
    else if constexpr (L == 3) asm volatile("s_waitcnt vmcnt(3) lgkmcnt(0)" ::: "memory");
    else asm volatile("s_waitcnt vmcnt(2) lgkmcnt(0)" ::: "memory");
  };
  auto compute = [&](int buf) {
    bf16x8 af[AccM], bfr[AccN];
#pragma unroll
    for (int i = 0; i < AccM; i++) af[i] = *(const bf16x8*)(&As[buf][(wm + i * 16 + r) * 32 + g * 8]);
#pragma unroll
    for (int j = 0; j < AccN; j++) bfr[j] = *(const bf16x8*)(&Bs[buf][(wn + j * 16 + r) * 32 + g * 8]);
#pragma unroll
    for (int i = 0; i < AccM; i++)
#pragma unroll
      for (int j = 0; j < AccN; j++) acc[i][j] = MFMA16(af[i], bfr[j], acc[i][j]);
  };

  const int NKT = K / 32;
  stage(0, 0);
  stage(32, 1);
  waitL();
  __builtin_amdgcn_s_barrier();
  __builtin_amdgcn_sched_barrier(0);
  for (int it = 0; it < NKT - 2; ++it) {
    stage((it + 2) * 32, (it + 2) % 3);
    compute(it % 3);
    waitL();
    __builtin_amdgcn_s_barrier();
    __builtin_amdgcn_sched_barrier(0);
  }
  compute((NKT - 2) % 3);
  asm volatile("s_waitcnt vmcnt(0) lgkmcnt(0)" ::: "memory");
  __builtin_amdgcn_s_barrier();
  __builtin_amdgcn_sched_barrier(0);
  compute((NKT - 1) % 3);

#pragma unroll
  for (int i = 0; i < AccM; i++)
#pragma unroll
    for (int j = 0; j < AccN; j++)
#pragma unroll
      for (int t = 0; t < 4; t++) {
        const int mg = bm + wm + i * 16 + g * 4 + t;
        const int ng = bn + wn + j * 16 + r;
        const float v = acc[i][j][t];
        if (MODE == 2) {
          ((float*)outp)[(size_t)mg * N + ng] = res[(size_t)mg * N + ng] + v + bias[ng];
        } else {
          const float hv = v + bias[ng];
          ((u16*)outp)[(size_t)mg * N + ng] = f2b(hv > 0.f ? hv : 0.f);
        }
      }
}

// ---------------- flash attention (r6 structure + mask fast-path) ----------------
__global__ __launch_bounds__(256, 4)
void attn_kernel(const u16* __restrict__ Q, const u16* __restrict__ Kb,
                 const u16* __restrict__ Vt, const float* __restrict__ mask,
                 u16* __restrict__ outc) {
  const int bid = blockIdx.x;
  const int bh = (bid & 7) * 4 + ((bid >> 3) & 3);  // 4 heads per XCD
  const int qt = bid >> 5;
  const int b = bh >> 4, h = bh & 15;
  const int tid = threadIdx.x, lane = tid & 63, w = tid >> 6;
  const int r = lane & 15, g = lane >> 4;
  const int qbase = qt * 64 + w * 16;
  const u16* Qp = Q + ((size_t)bh * SEQ + qbase) * DKK;
  const u16* Kp = Kb + (size_t)bh * SEQ * DKK;
  const u16* Vp = Vt + (size_t)bh * DKK * SEQ;
  const float* mk = mask + b * SEQ;

  const bf16x8 bq0 = *(const bf16x8*)(Qp + r * DKK + g * 8);
  const bf16x8 bq1 = *(const bf16x8*)(Qp + r * DKK + 32 + g * 8);

  __shared__ __align__(16) u16 Ks[2][64 * 64];
  __shared__ __align__(16) u16 Vs[2][64 * 64];

  const int srow8 = lane >> 3;
  const int sgr = (lane & 7) ^ srow8;
  const u16* kSrc1 = Kp + (size_t)(w * 16 + srow8) * DKK + sgr * 8;
  const u16* kSrc2 = kSrc1 + 8 * DKK;
  const u16* vSrc1 = Vp + (size_t)(w * 16 + srow8) * SEQ + sgr * 8;
  const u16* vSrc2 = vSrc1 + 8 * SEQ;

  f32x4 o[4];
#pragma unroll
  for (int i = 0; i < 4; i++) o[i] = (f32x4){0.f, 0.f, 0.f, 0.f};
  float lr = 0.f;
  const int keyr = r & 7;

  gload_lds16(kSrc1, &Ks[0][0] + w * 1024);
  gload_lds16(kSrc2, &Ks[0][0] + w * 1024 + 512);
  gload_lds16(vSrc1, &Vs[0][0] + w * 1024);
  gload_lds16(vSrc2, &Vs[0][0] + w * 1024 + 512);
  asm volatile("s_waitcnt vmcnt(0)" ::: "memory");
  __builtin_amdgcn_s_barrier();
  __builtin_amdgcn_sched_barrier(0);

  const int NT = SEQ / 64;

#define ATTN_STEP(IT, BUF)                                                         \
  do {                                                                             \
    if ((IT) + 1 < NT) {                                                           \
      const int nsk = ((IT) + 1) * 64;                                             \
      u16* kd = &Ks[(BUF) ^ 1][0] + w * 1024;                                      \
      gload_lds16(kSrc1 + (size_t)nsk * DKK, kd);                                  \
      gload_lds16(kSrc2 + (size_t)nsk * DKK, kd + 512);                            \
      u16* vd = &Vs[(BUF) ^ 1][0] + w * 1024;                                      \
      gload_lds16(vSrc1 + nsk, vd);                                                \
      gload_lds16(vSrc2 + nsk, vd + 512);                                          \
    }                                                                              \
    f32x4 s[4];                                                                    \
    __builtin_amdgcn_s_setprio(1);                                                 \
    _Pragma("unroll")                                                              \
    for (int ks = 0; ks < 4; ks++) {                                               \
      const bf16x8 ka0 = *(const bf16x8*)&Ks[BUF][(ks * 16 + r) * 64 + ((g ^ keyr) << 3)];        \
      const bf16x8 ka1 = *(const bf16x8*)&Ks[BUF][(ks * 16 + r) * 64 + (((g + 4) ^ keyr) << 3)];  \
      f32x4 z = (f32x4){0.f, 0.f, 0.f, 0.f};                                       \
      z = MFMA16(ka0, bq0, z);                                                     \
      z = MFMA16(ka1, bq1, z);                                                     \
      s[ks] = z;                                                                   \
    }                                                                              \
    __builtin_amdgcn_s_setprio(0);                                                 \
    const int sk = (IT) * 64;                                                      \
    float4 mmv[4];                                                                 \
    _Pragma("unroll")                                                              \
    for (int ks = 0; ks < 4; ks++) mmv[ks] = *(const float4*)(mk + sk + ks * 16 + 4 * g); \
    int ones = 1;                                                                  \
    _Pragma("unroll")                                                              \
    for (int ks = 0; ks < 4; ks++)                                                 \
      ones &= (mmv[ks].x == 1.f) & (mmv[ks].y == 1.f) & (mmv[ks].z == 1.f) & (mmv[ks].w == 1.f); \
    const bool fastm = __all(ones);                                                \
    float p[16];                                                                   \
    float rs = 0.f;                                                                \
    if (fastm) {                                                                   \
      _Pragma("unroll")                                                            \
      for (int ks = 0; ks < 4; ks++) {                                             \
        float e0 = __builtin_amdgcn_exp2f(s[ks][0]);                               \
        float e1 = __builtin_amdgcn_exp2f(s[ks][1]);                               \
        float e2 = __builtin_amdgcn_exp2f(s[ks][2]);                               \
        float e3 = __builtin_amdgcn_exp2f(s[ks][3]);                               \
        p[ks * 4 + 0] = e0; p[ks * 4 + 1] = e1;                                    \
        p[ks * 4 + 2] = e2; p[ks * 4 + 3] = e3;                                    \
        rs += e0 + e1 + e2 + e3;                                                   \
      }                                                                            \
    } else {                                                                       \
      _Pragma("unroll")                                                            \
      for (int ks = 0; ks < 4; ks++) {                                             \
        float pr0 = s[ks][0] * mmv[ks].x, pr1 = s[ks][1] * mmv[ks].y;              \
        float pr2 = s[ks][2] * mmv[ks].z, pr3 = s[ks][3] * mmv[ks].w;              \
        float e0 = (pr0 == 0.f) ? 0.f : __builtin_amdgcn_exp2f(pr0);               \
        float e1 = (pr1 == 0.f) ? 0.f : __builtin_amdgcn_exp2f(pr1);               \
        float e2 = (pr2 == 0.f) ? 0.f : __builtin_amdgcn_exp2f(pr2);               \
        float e3 = (pr3 == 0.f) ? 0.f : __builtin_amdgcn_exp2f(pr3);               \
        p[ks * 4 + 0] = e0; p[ks * 4 + 1] = e1;                                    \
        p[ks * 4 + 2] = e2; p[ks * 4 + 3] = e3;                                    \
        rs += e0 + e1 + e2 + e3;                                                   \
      }                                                                            \
    }                                                                              \
    rs += __shfl_xor(rs, 16);                                                      \
    rs += __shfl_xor(rs, 32);                                                      \
    lr += rs;                                                                      \
    unsigned wk[4][2];                                                             \
    _Pragma("unroll")                                                              \
    for (int ks = 0; ks < 4; ks++) {                                               \
      wk[ks][0] = cvtpk(p[ks * 4 + 0], p[ks * 4 + 1]);                             \
      wk[ks][1] = cvtpk(p[ks * 4 + 2], p[ks * 4 + 3]);                             \
    }                                                                              \
    bf16x8 pa[2];                                                                  \
    _Pragma("unroll")                                                              \
    for (int hh2 = 0; hh2 < 2; hh2++) {                                            \
      union { unsigned u[4]; bf16x8 v; } pu;                                       \
      _Pragma("unroll")                                                            \
      for (int c = 0; c < 4; c++) {                                                \
        const int srcl = r + ((g & 1) * 2 + (c >> 1)) * 16;                        \
        const unsigned lo = __shfl(wk[2 * hh2][c & 1], srcl);                      \
        const unsigned hi = __shfl(wk[2 * hh2 + 1][c & 1], srcl);                  \
        pu.u[c] = (g < 2) ? lo : hi;                                               \
      }                                                                            \
      pa[hh2] = pu.v;                                                              \
    }                                                                              \
    __builtin_amdgcn_s_setprio(1);                                                 \
    _Pragma("unroll")                                                              \
    for (int dc = 0; dc < 4; dc++) {                                               \
      const int vr = dc * 16 + r;                                                  \
      const bf16x8 bv0 = *(const bf16x8*)&Vs[BUF][vr * 64 + ((g ^ keyr) << 3)];    \
      const bf16x8 bv1 = *(const bf16x8*)&Vs[BUF][vr * 64 + (((g + 4) ^ keyr) << 3)]; \
      o[dc] = MFMA16(pa[0], bv0, o[dc]);                                           \
      o[dc] = MFMA16(pa[1], bv1, o[dc]);                                           \
    }                                                                              \
    __builtin_amdgcn_s_setprio(0);                                                 \
    asm volatile("s_waitcnt vmcnt(0) lgkmcnt(0)" ::: "memory");                    \
    __builtin_amdgcn_s_barrier();                                                  \
    __builtin_amdgcn_sched_barrier(0);                                             \
  } while (0)

  for (int it = 0; it < NT; it += 2) {
    ATTN_STEP(it, 0);
    ATTN_STEP(it + 1, 1);
  }
#undef ATTN_STEP

  float lq[4];
#pragma unroll
  for (int t = 0; t < 4; t++) lq[t] = __shfl(lr, 4 * g + t);
#pragma unroll
  for (int dc = 0; dc < 4; dc++)
#pragma unroll
    for (int t = 0; t < 4; t++) {
      const int srow_g = qbase + g * 4 + t;
      outc[((size_t)(b * SEQ + srow_g)) * DM + h * DKK + dc * 16 + r] = f2b(o[dc][t] / lq[t]);
    }
}

extern "C" void kernel_launch(void* const* d_in, const int* in_sizes, int n_in,
                              void* d_out, int out_size, void* d_ws, size_t ws_size,
                              hipStream_t stream) {
  const float* x    = (const float*)d_in[0];
  const float* mask = (const float*)d_in[1];
  const float* Wq   = (const float*)d_in[2];
  const float* Wk   = (const float*)d_in[3];
  const float* Wv   = (const float*)d_in[4];
  const float* Wo   = (const float*)d_in[5];
  const float* bo   = (const float*)d_in[6];
  const float* W1   = (const float*)d_in[7];
  const float* b1   = (const float*)d_in[8];
  const float* W2   = (const float*)d_in[9];
  const float* b2   = (const float*)d_in[10];
  const float* l1a  = (const float*)d_in[11];
  const float* l1b  = (const float*)d_in[12];
  const float* l2a  = (const float*)d_in[13];
  const float* l2b  = (const float*)d_in[14];

  char* wsb = (char*)d_ws;
  u16* Wqkt = (u16*)(wsb + (0ull << 20));
  u16* Wvt  = (u16*)(wsb + (4ull << 20));
  u16* Wot  = (u16*)(wsb + (6ull << 20));
  u16* W1t  = (u16*)(wsb + (8ull << 20));
  u16* W2t  = (u16*)(wsb + (12ull << 20));
  u16* x2   = (u16*)(wsb + (16ull << 20));
  u16* qkb  = (u16*)(wsb + (24ull << 20));
  u16* vtb  = (u16*)(wsb + (40ull << 20));
  float* x1 = (float*)(wsb + (48ull << 20));
  u16* concat = x2;
  u16* x2b = qkb;
  u16* hb  = (u16*)(wsb + (32ull << 20));

  const float qscale = 0.125f * 1.4426950408889634f;

  prep_all<<<dim3(12288), 256, 0, stream>>>(Wq, Wk, Wv, Wo, W1, W2,
                                            Wqkt, Wvt, Wot, W1t, W2t,
                                            x, l1a, l1b, x2);

  qkv_gemm<<<dim3(1536), 256, 0, stream>>>(x2, Wqkt, Wvt, qkb, vtb, qscale);

  attn_kernel<<<dim3(1024), 256, 0, stream>>>(qkb, qkb + (size_t)TOK * DM, vtb, mask, concat);

  gemm_bt<2, 64, 64><<<dim3(TOK / 64, DM / 64), 256, 0, stream>>>(
      concat, Wot, TOK, DM, DM, bo, x, x1);

  ln_kernel<<<TOK, 256, 0, stream>>>(x1, l2a, l2b, x2b);

  gemm_bt<3, 64, 128><<<dim3(TOK / 64, DFF / 128), 256, 0, stream>>>(
      x2b, W1t, TOK, DFF, DM, b1, nullptr, hb);
  gemm_bt<2, 64, 64><<<dim3(TOK / 64, DM / 64), 256, 0, stream>>>(
      hb, W2t, TOK, DM, DFF, b2, x1, (float*)d_out);
}